// Round 3
// baseline (226.505 us; speedup 1.0000x reference)
//
#include <hip/hip_runtime.h>
#include <math.h>

#define NC   1000        // NUM_CLASSES
#define NV4  250         // float4 chunks per row (1000/4)
#define RPB  4           // rows per block (1 wave each)

typedef float fvec4 __attribute__((ext_vector_type(4)));  // native vector: OK for nontemporal builtins

__device__ __forceinline__ float fast_sigmoid(float x) {
    return 1.0f / (1.0f + __expf(-x));   // v_exp_f32 path
}

__global__ __launch_bounds__(256)
void smooth_filter_kernel(const float* __restrict__ in, float* __restrict__ out, int nrows) {
    const int wave = threadIdx.x >> 6;
    const int lane = threadIdx.x & 63;
    const int row  = blockIdx.x * RPB + wave;
    if (row >= nrows) return;

    const fvec4* __restrict__ rp = (const fvec4*)(in  + (size_t)row * NC);
    fvec4*       __restrict__ wp = (fvec4*)      (out + (size_t)row * NC);

    // Each lane loads up to 4 float4s: indices lane, lane+64, lane+128, lane+192 (<250)
    fvec4 v[4];
    float s_r = 0.f, s_a = 0.f, s_a2 = 0.f;
    #pragma unroll
    for (int j = 0; j < 4; ++j) {
        const int idx = lane + 64 * j;
        v[j] = (fvec4)(0.f);
        if (idx < NV4) v[j] = rp[idx];
        const float a0 = fabsf(v[j].x), a1 = fabsf(v[j].y),
                    a2 = fabsf(v[j].z), a3 = fabsf(v[j].w);
        s_r  += (v[j].x + v[j].y) + (v[j].z + v[j].w);
        s_a  += (a0 + a1) + (a2 + a3);
        s_a2 += (a0 * a0 + a1 * a1) + (a2 * a2 + a3 * a3);
    }

    // Butterfly reduction across the wave: every lane ends with the totals.
    #pragma unroll
    for (int m = 32; m > 0; m >>= 1) {
        s_r  += __shfl_xor(s_r,  m, 64);
        s_a  += __shfl_xor(s_a,  m, 64);
        s_a2 += __shfl_xor(s_a2, m, 64);
    }

    const float mean    = s_a * (1.0f / NC);
    const float var     = (s_a2 - (float)NC * mean * mean) * (1.0f / (NC - 1));
    const float inv_std = rsqrtf(var);
    const float c       = 1.0f / (NC - 1);

    #pragma unroll
    for (int j = 0; j < 4; ++j) {
        const int idx = lane + 64 * j;
        if (idx < NV4) {
            fvec4 o;
            o.x = v[j].x + fast_sigmoid((fabsf(v[j].x) - mean) * inv_std) * c * (s_r - (float)NC * v[j].x);
            o.y = v[j].y + fast_sigmoid((fabsf(v[j].y) - mean) * inv_std) * c * (s_r - (float)NC * v[j].y);
            o.z = v[j].z + fast_sigmoid((fabsf(v[j].z) - mean) * inv_std) * c * (s_r - (float)NC * v[j].z);
            o.w = v[j].w + fast_sigmoid((fabsf(v[j].w) - mean) * inv_std) * c * (s_r - (float)NC * v[j].w);
            __builtin_nontemporal_store(o, wp + idx);   // output never re-read
        }
    }
}

extern "C" void kernel_launch(void* const* d_in, const int* in_sizes, int n_in,
                              void* d_out, int out_size, void* d_ws, size_t ws_size,
                              hipStream_t stream) {
    const float* in  = (const float*)d_in[0];
    float*       out = (float*)d_out;
    const int nrows  = in_sizes[0] / NC;              // 32768
    const int blocks = (nrows + RPB - 1) / RPB;       // 8192
    smooth_filter_kernel<<<blocks, 256, 0, stream>>>(in, out, nrows);
}